// Round 6
// baseline (11992.944 us; speedup 1.0000x reference)
//
#include <hip/hip_runtime.h>
#include <hip/hip_bf16.h>

// Problem constants
#define NNEUR 8192
#define NCONV 64
#define LYC   36
#define LXC   36
#define BATCH 256
#define KRAW  1296   // 36*36
#define KITER 42     // K padded to 42*32 = 1344
#define BK    32
#define MROWS 16384  // BATCH*NCONV
#define BM 512
#define BN 512
// k-major staged layout per (tile, iter): 4 regions (c = 8-half k-subblock),
// each 512 rows x 8 halfs. 2048 chunks of 16 B per tile-iter = 16384 halfs.
#define IT_H   16384
#define TILE_H (KITER * IT_H)  // 688128 halfs per (m- or n-) tile
#define A_NTILES 32
#define B_NTILES 16
#define A_PREP_BLOCKS (A_NTILES * KITER)  // 1344
#define B_PREP_BLOCKS 64                  // 8192 / 128 neurons per block

typedef __attribute__((ext_vector_type(8))) _Float16 half8;
typedef __attribute__((ext_vector_type(4))) float f32x4;
typedef __attribute__((ext_vector_type(16))) float f32x16;

__device__ __forceinline__ void async_copy16(const void* g, void* l) {
  __builtin_amdgcn_global_load_lds(
      (const __attribute__((address_space(1))) void*)g,
      (__attribute__((address_space(3))) void*)l, 16, 0, 0);
}

// Prep. A blocks: one per (mtile, iter) — coalesced float4 conv loads -> LDS
// transpose -> contiguous k-major half8 stores. B blocks: one per 128 neurons
// — stage Wy/Wx rows in LDS (coalesced), compute Wyx*256 from LDS, store
// k-major. Padded LDS strides keep both conflict-free.
__global__ __launch_bounds__(256) void prep_kernel(
    const float* __restrict__ conv, const float* __restrict__ Wy,
    const float* __restrict__ Wx, _Float16* __restrict__ A,
    _Float16* __restrict__ B) {
  __shared__ char smraw[40960];
  const int t = threadIdx.x;
  if (blockIdx.x < A_PREP_BLOCKS) {  // ---- A: (mtile, it), 512 rows x 32 k
    _Float16* sm = (_Float16*)smraw;  // [512][40] halfs (stride-40 pad)
    const int tile = blockIdx.x / KITER;
    const int it = blockIdx.x - tile * KITER;
#pragma unroll
    for (int i = 0; i < 16; i++) {  // 512 rows x 8 float4
      const int idx = i * 256 + t;
      const int r = idx >> 3, j = idx & 7;
      const int k0 = it * BK + j * 4;
      float4 f = make_float4(0.f, 0.f, 0.f, 0.f);
      if (k0 < KRAW)  // KRAW%4==0: float4 never straddles the edge
        f = *(const float4*)(conv + (size_t)(tile * BM + r) * KRAW + k0);
      _Float16* d = sm + r * 40 + j * 4;
      d[0] = (_Float16)f.x; d[1] = (_Float16)f.y;
      d[2] = (_Float16)f.z; d[3] = (_Float16)f.w;
    }
    __syncthreads();
#pragma unroll
    for (int i = 0; i < 8; i++) {  // 2048 chunks, k-major (c fast over 512 r)
      const int idx = i * 256 + t;
      const int c = idx >> 9, r = idx & 511;
      const _Float16* s = sm + r * 40 + c * 8;
      half8 h;
#pragma unroll
      for (int e = 0; e < 8; e++) h[e] = s[e];
      *(half8*)(A + (size_t)tile * TILE_H + (size_t)it * IT_H +
                (size_t)idx * 8) = h;
    }
  } else {  // ---- B: 128 neurons per block, all 42 iters
    float* wy = (float*)smraw;        // [128][37] (stride-37 pad)
    float* wx = wy + 128 * 37;
    const int b = blockIdx.x - A_PREP_BLOCKS;  // 0..63
    const int ntile = b >> 2, q = b & 3;       // quarter of the 512-row tile
    const int nbase = ntile * BN + q * 128;
    for (int idx = t; idx < 128 * 36; idx += 256) {  // coalesced loads
      const int r = idx / 36, y = idx - r * 36;
      wy[r * 37 + y] = Wy[(size_t)(nbase + r) * LYC + y];
      wx[r * 37 + y] = Wx[(size_t)(nbase + r) * LXC + y];
    }
    __syncthreads();
    const int rloc = t & 127, grp = t >> 7;
    const float* myy = wy + rloc * 37;
    const float* myx = wx + rloc * 37;
    for (int it = grp; it < KITER; it += 2) {
#pragma unroll
      for (int c = 0; c < 4; c++) {
        const int k0 = it * BK + c * 8;
        half8 h;
#pragma unroll
        for (int e = 0; e < 8; e++) {
          const int k = k0 + e;
          float v = 0.f;
          if (k < KRAW) {
            const int y = k / LXC;
            const int x = k - y * LXC;
            v = myy[y] * myx[x] * 256.f;
          }
          h[e] = (_Float16)v;
        }
        *(half8*)(B + (size_t)ntile * TILE_H + (size_t)it * IT_H +
                  (size_t)(c * 512 + q * 128 + rloc) * 8) = h;
      }
    }
  }
}

// Fused GEMM: block 512x512, 1024 threads, 16 waves (4x4), wave-tile 128x128
// (acc[4][4] f32x16 = 256 AGPR). BK=32, double-buffered 2x64 KB dynamic LDS,
// one barrier per iter (DMA for it+1 in flight during compute on it).
// k-major LDS -> conflict-free contiguous fragment reads. Epilogue contracts
// the 64 channels with Wc, adds bias, ELU.
__global__ __launch_bounds__(1024, 1) void gemm_fused_kernel(
    const _Float16* __restrict__ A, const _Float16* __restrict__ B,
    const float* __restrict__ Wc, const float* __restrict__ bias,
    float* __restrict__ out) {
  extern __shared__ _Float16 lds[];  // 2 buffers x 32768 halfs (A|B)

  // XCD swizzle: xcd = bid&7 owns 2 n-tiles (B panel 2.75 MB, L2-resident);
  // consecutive block pairs share an A-tile.
  const int bid = blockIdx.x;  // 0..511
  const int l = bid >> 3;      // 0..63
  const int ntile = (bid & 7) * 2 + (l & 1);  // 0..15
  const int mtile = l >> 1;                   // 0..31

  const int t = threadIdx.x;
  const int lane = t & 63;
  const int wave = t >> 6;                  // 0..15
  const int wm = wave >> 2, wn = wave & 3;  // 4x4; wave tile 128x128
  const int r32 = lane & 31, hh = lane >> 5;

  f32x16 acc[4][4] = {};  // [mb][nb]

  const _Float16* pA = A + (size_t)mtile * TILE_H + t * 8;
  const _Float16* pB = B + (size_t)ntile * TILE_H + t * 8;

  // Prologue: stage iter 0 into buffer 0.
#pragma unroll
  for (int i = 0; i < 2; i++)
    async_copy16(pA + i * 8192, lds + t * 8 + i * 8192);
#pragma unroll
  for (int i = 0; i < 2; i++)
    async_copy16(pB + i * 8192, lds + 16384 + t * 8 + i * 8192);

  int cur = 0;
  for (int it = 0; it < KITER; ++it) {
    __syncthreads();  // own-wave vmcnt(0) drain completes buf[cur] DMA
    if (it + 1 < KITER) {
      const _Float16* nA = pA + (size_t)(it + 1) * IT_H;
      const _Float16* nB = pB + (size_t)(it + 1) * IT_H;
      _Float16* dA = lds + (cur ^ 1) * 32768 + t * 8;
      _Float16* dB = dA + 16384;
#pragma unroll
      for (int i = 0; i < 2; i++) async_copy16(nA + i * 8192, dA + i * 8192);
#pragma unroll
      for (int i = 0; i < 2; i++) async_copy16(nB + i * 8192, dB + i * 8192);
    }
    const _Float16* As_ = lds + cur * 32768;
    const _Float16* Bs_ = As_ + 16384;
#pragma unroll
    for (int ks = 0; ks < 2; ++ks) {
      const int cc = 2 * ks + hh;  // k-subblock for this lane-half
      half8 af[4], bf[4];
#pragma unroll
      for (int mb = 0; mb < 4; mb++)
        af[mb] =
            *(const half8*)(As_ + (cc * 512 + wm * 128 + mb * 32 + r32) * 8);
#pragma unroll
      for (int nb = 0; nb < 4; nb++)
        bf[nb] =
            *(const half8*)(Bs_ + (cc * 512 + wn * 128 + nb * 32 + r32) * 8);
#pragma unroll
      for (int mb = 0; mb < 4; mb++)
#pragma unroll
        for (int nb = 0; nb < 4; nb++)
          acc[mb][nb] = __builtin_amdgcn_mfma_f32_32x32x16_f16(
              af[mb], bf[nb], acc[mb][nb], 0, 0, 0);
    }
    cur ^= 1;
  }

  // Epilogue. C/D 32x32: col = lane&31, row = (reg&3)+8*(reg>>2)+4*hh.
  // Wave's 128 M-rows = 2 images x 64 channels; mb 0,1 -> img0, mb 2,3 -> img1.
  const int ibase = mtile * 8 + wm * 2;
  float v[2][4];  // [img][nb]
#pragma unroll
  for (int nb = 0; nb < 4; nb++) {
    const int n_g = ntile * BN + wn * 128 + nb * 32 + r32;
    const float* wc = Wc + (size_t)n_g * NCONV;
    f32x4 w[2][4];
#pragma unroll
    for (int hf = 0; hf < 2; hf++)
#pragma unroll
      for (int g = 0; g < 4; g++)
        w[hf][g] = *(const f32x4*)(wc + hf * 32 + hh * 4 + g * 8);
#pragma unroll
    for (int img = 0; img < 2; img++) {
      float p = 0.f;
#pragma unroll
      for (int hf = 0; hf < 2; hf++)
#pragma unroll
        for (int g = 0; g < 4; g++)
#pragma unroll
          for (int q = 0; q < 4; q++)
            p += acc[img * 2 + hf][nb][g * 4 + q] * w[hf][g][q];
      p += __shfl_xor(p, 32);  // combine the two row-halves
      v[img][nb] = p;
    }
  }
  const int img = ibase + hh;  // lane writes its own half's image
#pragma unroll
  for (int nb = 0; nb < 4; nb++) {
    const int n_out = ntile * BN + wn * 128 + nb * 32 + r32;
    float z = v[hh][nb] * 0.00390625f + bias[n_out];  // undo x256 scaling
    z = z > 0.f ? z : (__expf(z) - 1.f);
    out[(size_t)img * NNEUR + n_out] = z;
  }
}

extern "C" void kernel_launch(void* const* d_in, const int* in_sizes, int n_in,
                              void* d_out, int out_size, void* d_ws,
                              size_t ws_size, hipStream_t stream) {
  const float* conv = (const float*)d_in[0];
  const float* Wc = (const float*)d_in[1];
  const float* Wy = (const float*)d_in[2];
  const float* Wx = (const float*)d_in[3];
  const float* bias = (const float*)d_in[4];
  float* out = (float*)d_out;

  _Float16* Abuf = (_Float16*)d_ws;  // 32 tiles * 688128 halfs = 44.0 MB
  _Float16* Bbuf =
      (_Float16*)((char*)d_ws + (size_t)A_NTILES * TILE_H * 2);  // 22.0 MB

  static bool attr_set = false;  // idempotent; safe under graph capture
  if (!attr_set) {
    hipFuncSetAttribute((const void*)gemm_fused_kernel,
                        hipFuncAttributeMaxDynamicSharedMemorySize, 131072);
    attr_set = true;
  }

  prep_kernel<<<A_PREP_BLOCKS + B_PREP_BLOCKS, 256, 0, stream>>>(conv, Wy, Wx,
                                                                 Abuf, Bbuf);
  gemm_fused_kernel<<<512, 1024, 131072, stream>>>(Abuf, Bbuf, Wc, bias, out);
}

// Round 7
// 601.930 us; speedup vs baseline: 19.9242x; 19.9242x over previous
//
#include <hip/hip_runtime.h>
#include <hip/hip_bf16.h>

// Problem constants
#define NNEUR 8192
#define NCONV 64
#define LYC   36
#define LXC   36
#define BATCH 256
#define KRAW  1296   // 36*36
#define KITER 42     // K padded to 42*32 = 1344
#define BK    32
#define MROWS 16384  // BATCH*NCONV
// Packed k-major layout in 512-row tiles: per (tile, iter) 4 regions
// (c = 8-half k-subblock), each 512 rows x 8 halfs.
#define IT_H   16384                      // halfs per tile-iter
#define TILE_H (KITER * IT_H)             // 688128 halfs per 512-tile
#define A_NTILES 32                       // 16384/512
#define B_NTILES 16                       // 8192/512
#define A_PREP_BLOCKS (A_NTILES * KITER)  // 1344
#define B_PREP_BLOCKS (64 * 7)            // 64 neuron-groups x 7 it-chunks

typedef __attribute__((ext_vector_type(8))) _Float16 half8;
typedef __attribute__((ext_vector_type(4))) float f32x4;
typedef __attribute__((ext_vector_type(16))) float f32x16;

// Prep. A: one block per (mtile, it) — coalesced float4 conv loads -> LDS
// transpose -> k-major half8 stores. B: one block per (128-neuron group,
// 6-iter chunk) — Wy/Wx staged in padded LDS (coalesced), Wyx*256 stored
// k-major. All GEMM-side reads of these buffers are contiguous per half-wave.
__global__ __launch_bounds__(256) void prep_kernel(
    const float* __restrict__ conv, const float* __restrict__ Wy,
    const float* __restrict__ Wx, _Float16* __restrict__ A,
    _Float16* __restrict__ B) {
  __shared__ char smraw[40960];
  const int t = threadIdx.x;
  if (blockIdx.x < A_PREP_BLOCKS) {  // ---- A: (mtile, it), 512 rows x 32 k
    _Float16* sm = (_Float16*)smraw;  // [512][40] halfs (stride-40 pad)
    const int tile = blockIdx.x / KITER;
    const int it = blockIdx.x - tile * KITER;
#pragma unroll
    for (int i = 0; i < 16; i++) {  // 512 rows x 8 float4
      const int idx = i * 256 + t;
      const int r = idx >> 3, j = idx & 7;
      const int k0 = it * BK + j * 4;
      float4 f = make_float4(0.f, 0.f, 0.f, 0.f);
      if (k0 < KRAW)  // KRAW%4==0: float4 never straddles the edge
        f = *(const float4*)(conv + (size_t)(tile * 512 + r) * KRAW + k0);
      _Float16* d = sm + r * 40 + j * 4;
      d[0] = (_Float16)f.x; d[1] = (_Float16)f.y;
      d[2] = (_Float16)f.z; d[3] = (_Float16)f.w;
    }
    __syncthreads();
#pragma unroll
    for (int i = 0; i < 8; i++) {  // 2048 chunks, k-major (c slow, r fast)
      const int idx = i * 256 + t;
      const int c = idx >> 9, r = idx & 511;
      const _Float16* s = sm + r * 40 + c * 8;
      half8 h;
#pragma unroll
      for (int e = 0; e < 8; e++) h[e] = s[e];
      *(half8*)(A + (size_t)tile * TILE_H + (size_t)it * IT_H +
                (size_t)idx * 8) = h;
    }
  } else {  // ---- B: (neuron-group of 128, 6-iter chunk)
    float* wy = (float*)smraw;  // [128][37] f32 (padded)
    float* wx = wy + 128 * 37;
    const int b = blockIdx.x - A_PREP_BLOCKS;  // 0..447
    const int group = b / 7, itc = b - group * 7;
    const int ntile = group >> 2, q = group & 3;
    const int nbase = ntile * 512 + q * 128;
    for (int idx = t; idx < 128 * 36; idx += 256) {  // coalesced stage
      const int r = idx / 36, y = idx - r * 36;
      wy[r * 37 + y] = Wy[(size_t)(nbase + r) * LYC + y];
      wx[r * 37 + y] = Wx[(size_t)(nbase + r) * LXC + y];
    }
    __syncthreads();
    const int rloc = t & 127, grp = t >> 7;
    const float* myy = wy + rloc * 37;
    const float* myx = wx + rloc * 37;
#pragma unroll
    for (int s = 0; s < 3; s++) {
      const int it = itc * 6 + grp * 3 + s;
#pragma unroll
      for (int c = 0; c < 4; c++) {
        const int k0 = it * BK + c * 8;
        half8 h;
#pragma unroll
        for (int e = 0; e < 8; e++) {
          const int k = k0 + e;
          float v = 0.f;
          if (k < KRAW) {
            const int y = k / LXC;
            const int x = k - y * LXC;
            v = myy[y] * myx[x] * 256.f;
          }
          h[e] = (_Float16)v;
        }
        *(half8*)(B + (size_t)ntile * TILE_H + (size_t)it * IT_H +
                  (size_t)(c * 512 + q * 128 + rloc) * 8) = h;
      }
    }
  }
}

// Fused GEMM, barrier-free: operands are pre-packed in MFMA fragment order,
// so each wave streams af/bf fragments straight from global (L1/L2) into
// VGPRs — no LDS, no __syncthreads, register ping-pong prefetch (AITER-style
// fine-grained vmcnt instead of barrier drains). Block = 4 waves (2x2) for
// L1 sharing; wave-tile 128x128, acc = 256 AGPR, 1 wave/SIMD.
__global__ __launch_bounds__(256, 1) void gemm_fused_kernel(
    const _Float16* __restrict__ A, const _Float16* __restrict__ B,
    const float* __restrict__ Wc, const float* __restrict__ bias,
    float* __restrict__ out) {
  // XCD swizzle: xcd = bid&7 owns 4 n-blocks (B panel 2.75 MB, L2-resident);
  // n varies fastest within an XCD so concurrent blocks share A-tiles.
  const int bid = blockIdx.x;  // 0..2047
  const int local = bid >> 3;  // 0..255
  const int nblk = (bid & 7) * 4 + (local & 3);  // 0..31 (256-col blocks)
  const int mblk = local >> 2;                   // 0..63 (256-row blocks)

  const int t = threadIdx.x;
  const int lane = t & 63;
  const int wave = t >> 6;                  // 0..3
  const int wm = wave >> 1, wn = wave & 1;  // 2x2; wave tile 128x128
  const int r32 = lane & 31, hh = lane >> 5;

  const int arow = (mblk & 1) * 256 + wm * 128 + r32;
  const int brow = (nblk & 1) * 256 + wn * 128 + r32;
  // Fragment pointers: element (row, k = it*32 + cc*8 + j) lives at
  // tile*TILE_H + it*IT_H + (cc*512 + row)*8;  cc = 2*ks + hh.
  const _Float16* pA0 = A + (size_t)(mblk >> 1) * TILE_H + hh * 4096 + arow * 8;
  const _Float16* pA1 = pA0 + 8192;  // ks=1
  const _Float16* pB0 = B + (size_t)(nblk >> 1) * TILE_H + hh * 4096 + brow * 8;
  const _Float16* pB1 = pB0 + 8192;

  f32x16 acc[4][4] = {};  // [mb][nb]

  half8 fa0[8], fb0[8], fa1[8], fb1[8];  // [ks*4 + mb/nb]

  auto loadf = [&](half8* fa, half8* fb, int it) {
    const size_t off = (size_t)it * IT_H;
#pragma unroll
    for (int mb = 0; mb < 4; mb++) {
      fa[mb] = *(const half8*)(pA0 + off + mb * 256);
      fa[4 + mb] = *(const half8*)(pA1 + off + mb * 256);
    }
#pragma unroll
    for (int nb = 0; nb < 4; nb++) {
      fb[nb] = *(const half8*)(pB0 + off + nb * 256);
      fb[4 + nb] = *(const half8*)(pB1 + off + nb * 256);
    }
  };
  auto compute = [&](const half8* fa, const half8* fb) {
#pragma unroll
    for (int ks = 0; ks < 2; ks++)
#pragma unroll
      for (int mb = 0; mb < 4; mb++)
#pragma unroll
        for (int nb = 0; nb < 4; nb++)
          acc[mb][nb] = __builtin_amdgcn_mfma_f32_32x32x16_f16(
              fa[ks * 4 + mb], fb[ks * 4 + nb], acc[mb][nb], 0, 0, 0);
  };

  loadf(fa0, fb0, 0);
  for (int it = 0; it < KITER; it += 2) {
    loadf(fa1, fb1, it + 1);  // it+1 <= 41 always (KITER even)
    compute(fa0, fb0);
    if (it + 2 < KITER) loadf(fa0, fb0, it + 2);
    compute(fa1, fb1);
  }

  // Epilogue. C/D 32x32: col = lane&31, row = (reg&3)+8*(reg>>2)+4*hh.
  // Wave's 128 M-rows = 2 images x 64 channels; mb 0,1 -> img0, mb 2,3 -> img1.
  const int ibase = mblk * 4 + wm * 2;
  float v[2][4];  // [img][nb]
#pragma unroll
  for (int nb = 0; nb < 4; nb++) {
    const int n_g = nblk * 256 + wn * 128 + nb * 32 + r32;
    const float* wc = Wc + (size_t)n_g * NCONV;
    f32x4 w[2][4];
#pragma unroll
    for (int hf = 0; hf < 2; hf++)
#pragma unroll
      for (int g = 0; g < 4; g++)
        w[hf][g] = *(const f32x4*)(wc + hf * 32 + hh * 4 + g * 8);
#pragma unroll
    for (int img = 0; img < 2; img++) {
      float p = 0.f;
#pragma unroll
      for (int hf = 0; hf < 2; hf++)
#pragma unroll
        for (int g = 0; g < 4; g++)
#pragma unroll
          for (int q = 0; q < 4; q++)
            p += acc[img * 2 + hf][nb][g * 4 + q] * w[hf][g][q];
      p += __shfl_xor(p, 32);  // combine the two row-halves
      v[img][nb] = p;
    }
  }
  const int img = ibase + hh;  // lane writes its own half's image
#pragma unroll
  for (int nb = 0; nb < 4; nb++) {
    const int n_out = nblk * 256 + wn * 128 + nb * 32 + r32;
    float z = v[hh][nb] * 0.00390625f + bias[n_out];  // undo x256 scaling
    z = z > 0.f ? z : (__expf(z) - 1.f);
    out[(size_t)img * NNEUR + n_out] = z;
  }
}

extern "C" void kernel_launch(void* const* d_in, const int* in_sizes, int n_in,
                              void* d_out, int out_size, void* d_ws,
                              size_t ws_size, hipStream_t stream) {
  const float* conv = (const float*)d_in[0];
  const float* Wc = (const float*)d_in[1];
  const float* Wy = (const float*)d_in[2];
  const float* Wx = (const float*)d_in[3];
  const float* bias = (const float*)d_in[4];
  float* out = (float*)d_out;

  _Float16* Abuf = (_Float16*)d_ws;  // 32 tiles * 688128 halfs = 44.0 MB
  _Float16* Bbuf =
      (_Float16*)((char*)d_ws + (size_t)A_NTILES * TILE_H * 2);  // 22.0 MB

  prep_kernel<<<A_PREP_BLOCKS + B_PREP_BLOCKS, 256, 0, stream>>>(conv, Wy, Wx,
                                                                 Abuf, Bbuf);
  gemm_fused_kernel<<<2048, 256, 0, stream>>>(Abuf, Bbuf, Wc, bias, out);
}